// Round 9
// baseline (144.107 us; speedup 1.0000x reference)
//
#include <hip/hip_runtime.h>
#include <cstdint>
#include <cstddef>

#define NUSERS 100000
#define BB 16384

static __device__ __forceinline__ unsigned short f2bf(float x) {
    unsigned u = __float_as_uint(x);
    u += 0x7FFF + ((u >> 16) & 1);          // round-to-nearest-even
    return (unsigned short)(u >> 16);
}

// accumulate 8 bf16 values (packed in a uint4) into acc[8] with weight w
static __device__ __forceinline__ void acc8(float* acc, uint4 q, float w) {
    acc[0] += w * __uint_as_float(q.x << 16);
    acc[1] += w * __uint_as_float(q.x & 0xffff0000u);
    acc[2] += w * __uint_as_float(q.y << 16);
    acc[3] += w * __uint_as_float(q.y & 0xffff0000u);
    acc[4] += w * __uint_as_float(q.z << 16);
    acc[5] += w * __uint_as_float(q.z & 0xffff0000u);
    acc[6] += w * __uint_as_float(q.w << 16);
    acc[7] += w * __uint_as_float(q.w & 0xffff0000u);
}

// ---------------- K0: per-user attention score Q[u] AND bf16 feature table.
// (unchanged — streaming, ~8us)
__global__ __launch_bounds__(256) void k0_scores(
    const float* __restrict__ features, const float* __restrict__ wg1,
    const float* __restrict__ bg1, const float* __restrict__ wg2,
    const float* __restrict__ bg2, float* __restrict__ Q,
    unsigned short* __restrict__ fbf)
{
    __shared__ float frow[16 * 68];   // 16 user rows, padded
    __shared__ float wg1t[16 * 68];   // wg1 transposed [k][d], padded
    const int tid = threadIdx.x;
    const int blk = blockIdx.x;

    const float4 v = ((const float4*)(features + (size_t)blk * 1024))[tid];
    {
        const int row = tid >> 4, q = tid & 15;
        *(float4*)&frow[row * 68 + q * 4] = v;
    }
    {
        const float4 w = ((const float4*)wg1)[tid];
        const int d = tid >> 2, k0 = (tid & 3) * 4;
        wg1t[(k0 + 0) * 68 + d] = w.x;
        wg1t[(k0 + 1) * 68 + d] = w.y;
        wg1t[(k0 + 2) * 68 + d] = w.z;
        wg1t[(k0 + 3) * 68 + d] = w.w;
    }
    {
        ushort4 o;
        o.x = f2bf(v.x); o.y = f2bf(v.y); o.z = f2bf(v.z); o.w = f2bf(v.w);
        *(ushort4*)(fbf + (size_t)blk * 1024 + tid * 4) = o;
    }
    __syncthreads();

    const int k = tid & 15, ul = tid >> 4;
    float x = bg1[k];
    #pragma unroll
    for (int d4 = 0; d4 < 16; ++d4) {
        const float4 f  = *(const float4*)&frow[ul * 68 + d4 * 4];
        const float4 wv = *(const float4*)&wg1t[k * 68 + d4 * 4];
        x += f.x * wv.x + f.y * wv.y + f.z * wv.z + f.w * wv.w;
    }
    float xx = fminf(fmaxf(x, -9.f), 9.f);
    float e2 = __expf(2.f * xx);
    float th = (e2 - 1.f) / (e2 + 1.f);
    float t = th * wg2[k];
    t += __shfl_xor(t, 1);
    t += __shfl_xor(t, 2);
    t += __shfl_xor(t, 4);
    t += __shfl_xor(t, 8);
    if (k == 0) Q[blk * 16 + ul] = t + bg2[0];
}

// ---------------- K1: 1-wave workgroups + flat-burst gather.
// Rounds 6/7/8 tri-null: bytes, footprint, and per-iter issue width all
// failed to move the ~41us gather kernel; utilizations all low -> latency
// bound with capped residency (36% occ at BOTH 13KB and 18KB LDS suggests a
// ~3 workgroup/CU cap for 256-thread blocks, not an LDS/VGPR limit).
// This version probes both remaining levers at once:
//  - 64-thread blocks (1 wave = 1 element, 16384 blocks): if the cap is
//    block-slots/CU (~16), resident waves rise even at VGPR ~100.
//  - flat-burst gather: fixed 96-entry window (>= max n=82), all 12 offsets
//    computed upfront, all 12 8-row loads issued in one burst, consumed in
//    order (compiler stages vmcnt). One latency exposure instead of 2-3.
//    Tail entries read row 0 (single broadcast line, weight 0) — near-free.
__global__ __launch_bounds__(64) void k1_fuse(
    const int* __restrict__ nodes, const int* __restrict__ hist_u,
    const int* __restrict__ hist_r, const int* __restrict__ hist_m,
    const int* __restrict__ soc_a, const int* __restrict__ soc_m,
    const unsigned short* __restrict__ fbf, const float* __restrict__ r_embed,
    const float* __restrict__ Q, const float* __restrict__ w1,
    const float* __restrict__ b1, float* __restrict__ out)
{
    __shared__ float wvbuf[128];      // 512B per-block union:
                                      //   lifetime 1: lcomp int[96]
                                      //   lifetime 2: comb  float[128]

    const int lane = threadIdx.x;     // 0..63 (one wave)
    const int e    = blockIdx.x;
    const int sub  = lane & 15;       // matvec role
    const int grp  = lane >> 4;       // matvec role
    const int oct  = lane >> 3;       // gather row-slot 0..7
    const int s8   = lane & 7;        // gather dim-octet (dims s8*8..+7)
    const char* fb = (const char*)fbf;

    int*   lc = (int*)&wvbuf[0];
    float* cb = &wvbuf[0];

    // ---- zero-init merged list (tail entries: offset 0 = row 0) ----
    lc[lane] = 0;
    if (lane < 32) lc[64 + lane] = 0;

    // ---- index loads (issue ASAP) ----
    int nd = (lane < 8) ? nodes[e * 8 + lane] : 0;
    int hu = 0, hr = 0, hmv = 0;
    if (lane < 50) {
        hu  = hist_u[e * 50 + lane];
        hr  = hist_r[e * 50 + lane];
        hmv = hist_m[e * 50 + lane];
    }
    int sa = 0, sk = 0;
    if (lane < 32) {
        sa = soc_a[e * 32 + lane];
        sk = soc_m[e * 32 + lane];
    }

    // ---- ballots / counts ----
    uint64_t hb = __ballot(hmv != 0);
    const int hc = (int)__popcll(hb);
    int hrank = (int)__popcll(hb & ((1ull << lane) - 1));

    uint64_t sbm = __ballot(sk != 0);
    const int scn = (int)__popcll(sbm);
    int srank = (int)__popcll(sbm & ((1ull << lane) - 1));

    const float hw = 0.5f / (float)hc;     // hc >= 1 (mask[:,0]=True)
    const float sw = 0.5f / (float)scn;    // scn >= 1
    const int   n  = hc + scn;             // <= 82

    // ---- merged compaction: hist [0,hc), social [hc,n); byte offsets,
    //      bf16 row = 128B ----
    if (hmv) lc[hrank] = hu << 7;
    if (sk)  lc[hc + srank] = sa << 7;

    // ---- rating counts ----
    const int c0 = (int)__popcll(__ballot(hmv && hr == 0));
    const int c1 = (int)__popcll(__ballot(hmv && hr == 1));
    const int c2 = (int)__popcll(__ballot(hmv && hr == 2));
    const int c3 = (int)__popcll(__ballot(hmv && hr == 3));
    const int c4 = (int)__popcll(__ballot(hmv && hr == 4));

    // ---- read back merged list (ends lcomp lifetime) ----
    int pkA = lc[lane];
    int pkB = lc[64 + (lane & 31)];

    // ---- Q gather + member row: issued at the head of the burst ----
    float sc = (lane < 8) ? Q[nd] : -1e30f;
    const int um = __shfl(nd, oct);
    const uint4 mq = *(const uint4*)(fb + ((unsigned)um << 7) + s8 * 16);

    // ---- flat-burst neighbor gather: 12 independent 8-row loads, one
    //      issue burst, in-order consumption (staged vmcnt) ----
    int offs[12];
    #pragma unroll
    for (int j = 0; j < 12; ++j) {
        const int cb8 = j * 8;           // 0,8,..,88 (8-aligned: no straddle)
        offs[j] = (cb8 < 64) ? __shfl(pkA, cb8 + oct)
                             : __shfl(pkB, cb8 - 64 + oct);
    }
    uint4 q[12];
    #pragma unroll
    for (int j = 0; j < 12; ++j)
        q[j] = *(const uint4*)(fb + (unsigned)offs[j] + s8 * 16);

    float nb[8] = {0.f, 0.f, 0.f, 0.f, 0.f, 0.f, 0.f, 0.f};
    #pragma unroll
    for (int j = 0; j < 12; ++j) {
        const int idx = j * 8 + oct;
        const float w = (idx < hc) ? hw : ((idx < n) ? sw : 0.f);
        acc8(nb, q[j], w);
    }

    // ---- softmax over 8 group logits (lanes 0..7) ----
    float mx = sc;
    mx = fmaxf(mx, __shfl_xor(mx, 1));
    mx = fmaxf(mx, __shfl_xor(mx, 2));
    mx = fmaxf(mx, __shfl_xor(mx, 4));
    float ex = __expf(sc - mx);
    float sm = ex;
    sm += __shfl_xor(sm, 1);
    sm += __shfl_xor(sm, 2);
    sm += __shfl_xor(sm, 4);
    float al = ex / sm;                 // valid on lanes 0..7

    // ---- self half: alpha-weighted member row (slot oct) ----
    const float am = __shfl(al, oct);
    float sf[8] = {0.f, 0.f, 0.f, 0.f, 0.f, 0.f, 0.f, 0.f};
    acc8(sf, mq, am);

    // ---- cross-slot reduction: sum over oct (lane bits 3..5) ----
    #pragma unroll
    for (int k = 0; k < 8; ++k) {
        nb[k] += __shfl_xor(nb[k], 8);
        nb[k] += __shfl_xor(nb[k], 16);
        nb[k] += __shfl_xor(nb[k], 32);
        sf[k] += __shfl_xor(sf[k], 8);
        sf[k] += __shfl_xor(sf[k], 16);
        sf[k] += __shfl_xor(sf[k], 32);
    }

    // ---- rating-count correction (scaled by 0.5/hc), dims s8*8..+7 ----
    {
        const float4* r4 = (const float4*)r_embed;   // rows of 16 quads
        const int qa = s8 * 2;
        const float4 a0 = r4[0 * 16 + qa], b0 = r4[0 * 16 + qa + 1];
        const float4 a1 = r4[1 * 16 + qa], b1v = r4[1 * 16 + qa + 1];
        const float4 a2 = r4[2 * 16 + qa], b2v = r4[2 * 16 + qa + 1];
        const float4 a3 = r4[3 * 16 + qa], b3v = r4[3 * 16 + qa + 1];
        const float4 a4 = r4[4 * 16 + qa], b4v = r4[4 * 16 + qa + 1];
        const float f0 = hw * (float)c0, f1 = hw * (float)c1, f2 = hw * (float)c2,
                    f3 = hw * (float)c3, f4 = hw * (float)c4;
        nb[0] += f0 * a0.x + f1 * a1.x + f2 * a2.x + f3 * a3.x + f4 * a4.x;
        nb[1] += f0 * a0.y + f1 * a1.y + f2 * a2.y + f3 * a3.y + f4 * a4.y;
        nb[2] += f0 * a0.z + f1 * a1.z + f2 * a2.z + f3 * a3.z + f4 * a4.z;
        nb[3] += f0 * a0.w + f1 * a1.w + f2 * a2.w + f3 * a3.w + f4 * a4.w;
        nb[4] += f0 * b0.x + f1 * b1v.x + f2 * b2v.x + f3 * b3v.x + f4 * b4v.x;
        nb[5] += f0 * b0.y + f1 * b1v.y + f2 * b2v.y + f3 * b3v.y + f4 * b4v.y;
        nb[6] += f0 * b0.z + f1 * b1v.z + f2 * b2v.z + f3 * b3v.z + f4 * b4v.z;
        nb[7] += f0 * b0.w + f1 * b1v.w + f2 * b2v.w + f3 * b3v.w + f4 * b4v.w;
    }

    // ---- park comb row (lcomp dead; wave-local, no barrier) ----
    if (oct == 0) {
        *(float4*)&cb[s8 * 8]     = make_float4(sf[0], sf[1], sf[2], sf[3]);
        *(float4*)&cb[s8 * 8 + 4] = make_float4(sf[4], sf[5], sf[6], sf[7]);
    } else if (oct == 1) {
        *(float4*)&cb[64 + s8 * 8]     = make_float4(nb[0], nb[1], nb[2], nb[3]);
        *(float4*)&cb[64 + s8 * 8 + 4] = make_float4(nb[4], nb[5], nb[6], nb[7]);
    }

    // ---- fused matvec, float4 w1 loads:
    //      lane (grp,sub) accumulates cols 4sub..4sub+3 over k = 4j+grp ----
    float4 p = {0.f, 0.f, 0.f, 0.f};
    #pragma unroll 8
    for (int j = 0; j < 32; ++j) {
        const float  c   = cb[j * 4 + grp];                    // LDS broadcast
        const float4 wv4 = *(const float4*)(w1 + (j * 4 + grp) * 64 + sub * 4);
        p.x += c * wv4.x;
        p.y += c * wv4.y;
        p.z += c * wv4.z;
        p.w += c * wv4.w;
    }
    p.x += __shfl_xor(p.x, 16); p.x += __shfl_xor(p.x, 32);
    p.y += __shfl_xor(p.y, 16); p.y += __shfl_xor(p.y, 32);
    p.z += __shfl_xor(p.z, 16); p.z += __shfl_xor(p.z, 32);
    p.w += __shfl_xor(p.w, 16); p.w += __shfl_xor(p.w, 32);
    if (grp == 0) {
        const float4 bv = *(const float4*)(b1 + sub * 4);
        float4 o;
        o.x = fmaxf(p.x + bv.x, 0.f);
        o.y = fmaxf(p.y + bv.y, 0.f);
        o.z = fmaxf(p.z + bv.z, 0.f);
        o.w = fmaxf(p.w + bv.w, 0.f);
        *(float4*)(out + (size_t)e * 64 + sub * 4) = o;
    }
}

extern "C" void kernel_launch(void* const* d_in, const int* in_sizes, int n_in,
                              void* d_out, int out_size, void* d_ws, size_t ws_size,
                              hipStream_t stream)
{
    const int*   nodes    = (const int*)d_in[0];
    const int*   hu       = (const int*)d_in[1];
    const int*   hr       = (const int*)d_in[2];
    const int*   hm       = (const int*)d_in[3];
    const int*   sa       = (const int*)d_in[4];
    const int*   smk      = (const int*)d_in[5];
    const float* features = (const float*)d_in[6];
    const float* r_embed  = (const float*)d_in[7];
    const float* wg1      = (const float*)d_in[8];
    const float* bg1      = (const float*)d_in[9];
    const float* wg2      = (const float*)d_in[10];
    const float* bg2      = (const float*)d_in[11];
    const float* w1       = (const float*)d_in[12];
    const float* b1       = (const float*)d_in[13];
    float* out = (float*)d_out;

    float*          Q   = (float*)d_ws;                    // 131072 floats (512 KB)
    unsigned short* fbf = (unsigned short*)(Q + 131072);   // 100000*64 bf16 = 12.8 MB

    k0_scores<<<NUSERS / 16, 256, 0, stream>>>(features, wg1, bg1, wg2, bg2, Q, fbf);
    k1_fuse<<<BB, 64, 0, stream>>>(nodes, hu, hr, hm, sa, smk,
                                   fbf, r_embed, Q, w1, b1, out);
}

// Round 10
// 143.823 us; speedup vs baseline: 1.0020x; 1.0020x over previous
//
#include <hip/hip_runtime.h>
#include <cstdint>
#include <cstddef>

#define NUSERS 100000
#define BB 16384

static __device__ __forceinline__ unsigned short f2bf(float x) {
    unsigned u = __float_as_uint(x);
    u += 0x7FFF + ((u >> 16) & 1);          // round-to-nearest-even
    return (unsigned short)(u >> 16);
}
static __device__ __forceinline__ float4 bf4_to_f4(ushort4 h) {
    float4 r;
    r.x = __uint_as_float((unsigned)h.x << 16);
    r.y = __uint_as_float((unsigned)h.y << 16);
    r.z = __uint_as_float((unsigned)h.z << 16);
    r.w = __uint_as_float((unsigned)h.w << 16);
    return r;
}

// ---------------- K0: per-user attention score Q[u] AND bf16 feature table.
// (byte-identical to round 7 — streaming, ~8us)
__global__ __launch_bounds__(256) void k0_scores(
    const float* __restrict__ features, const float* __restrict__ wg1,
    const float* __restrict__ bg1, const float* __restrict__ wg2,
    const float* __restrict__ bg2, float* __restrict__ Q,
    unsigned short* __restrict__ fbf)
{
    __shared__ float frow[16 * 68];   // 16 user rows, padded
    __shared__ float wg1t[16 * 68];   // wg1 transposed [k][d], padded
    const int tid = threadIdx.x;
    const int blk = blockIdx.x;

    const float4 v = ((const float4*)(features + (size_t)blk * 1024))[tid];
    {
        const int row = tid >> 4, q = tid & 15;
        *(float4*)&frow[row * 68 + q * 4] = v;
    }
    {
        const float4 w = ((const float4*)wg1)[tid];
        const int d = tid >> 2, k0 = (tid & 3) * 4;
        wg1t[(k0 + 0) * 68 + d] = w.x;
        wg1t[(k0 + 1) * 68 + d] = w.y;
        wg1t[(k0 + 2) * 68 + d] = w.z;
        wg1t[(k0 + 3) * 68 + d] = w.w;
    }
    {
        ushort4 o;
        o.x = f2bf(v.x); o.y = f2bf(v.y); o.z = f2bf(v.z); o.w = f2bf(v.w);
        *(ushort4*)(fbf + (size_t)blk * 1024 + tid * 4) = o;
    }
    __syncthreads();

    const int k = tid & 15, ul = tid >> 4;
    float x = bg1[k];
    #pragma unroll
    for (int d4 = 0; d4 < 16; ++d4) {
        const float4 f  = *(const float4*)&frow[ul * 68 + d4 * 4];
        const float4 wv = *(const float4*)&wg1t[k * 68 + d4 * 4];
        x += f.x * wv.x + f.y * wv.y + f.z * wv.z + f.w * wv.w;
    }
    float xx = fminf(fmaxf(x, -9.f), 9.f);
    float e2 = __expf(2.f * xx);
    float th = (e2 - 1.f) / (e2 + 1.f);
    float t = th * wg2[k];
    t += __shfl_xor(t, 1);
    t += __shfl_xor(t, 2);
    t += __shfl_xor(t, 4);
    t += __shfl_xor(t, 8);
    if (k == 0) Q[blk * 16 + ul] = t + bg2[0];
}

// ---------------- K1: round-7 structure + DIAGNOSTIC gather-phase doubling.
// Four structural theories (bytes, footprint, occupancy, issue width/depth)
// all nulled; this is the pre-committed phase-ablation measurement round.
// The neighbor-gather loop runs TWICE: pass 1 is the real computation,
// pass 2 re-issues identical loads into a dummy accumulator. A compiler
// memory barrier between passes prevents load CSE; asm keep-alives prevent
// DCE (guide rule #17). Output math is untouched.
// Readout: dur_us - 138.5 = marginal gather-phase cost G; if k1+G > ~46us
// the kernel surfaces in top-5 with full PMC counters.
__global__ __launch_bounds__(256) void k1_fuse(
    const int* __restrict__ nodes, const int* __restrict__ hist_u,
    const int* __restrict__ hist_r, const int* __restrict__ hist_m,
    const int* __restrict__ soc_a, const int* __restrict__ soc_m,
    const unsigned short* __restrict__ fbf, const float* __restrict__ r_embed,
    const float* __restrict__ Q, const float* __restrict__ w1,
    const float* __restrict__ b1, float* __restrict__ out)
{
    __shared__ float wvbuf[4][128];   // 2048B per-wave union:
                                      //   lifetime 1: lcomp int[96]
                                      //   lifetime 2: comb  float[128]

    const int tid  = threadIdx.x;
    const int lane = tid & 63;
    const int wv   = tid >> 6;
    const int e    = blockIdx.x * 4 + wv;
    const int sub  = lane & 15;       // matvec role
    const int grp  = lane >> 4;       // matvec role
    const char* fb = (const char*)fbf;

    int*   lc = (int*)&wvbuf[wv][0];
    float* cb = &wvbuf[wv][0];

    // ---- zero-init merged list (tail entries: offset 0 = row 0) ----
    lc[lane] = 0;
    if (lane < 32) lc[64 + lane] = 0;

    // ---- index loads (issue ASAP) ----
    int nd = (lane < 8) ? nodes[e * 8 + lane] : 0;
    int hu = 0, hr = 0, hmv = 0;
    if (lane < 50) {
        hu  = hist_u[e * 50 + lane];
        hr  = hist_r[e * 50 + lane];
        hmv = hist_m[e * 50 + lane];
    }
    int sa = 0, sk = 0;
    if (lane < 32) {
        sa = soc_a[e * 32 + lane];
        sk = soc_m[e * 32 + lane];
    }

    // ---- ballots / counts ----
    uint64_t hb = __ballot(hmv != 0);
    const int hc = (int)__popcll(hb);
    int hrank = (int)__popcll(hb & ((1ull << lane) - 1));

    uint64_t sbm = __ballot(sk != 0);
    const int scn = (int)__popcll(sbm);
    int srank = (int)__popcll(sbm & ((1ull << lane) - 1));

    const float hw = 0.5f / (float)hc;     // hc >= 1 (mask[:,0]=True)
    const float sw = 0.5f / (float)scn;    // scn >= 1
    const int   n  = hc + scn;             // <= 82

    // ---- merged compaction: hist [0,hc), social [hc,n); byte offsets,
    //      bf16 row = 128B ----
    if (hmv) lc[hrank] = hu << 7;
    if (sk)  lc[hc + srank] = sa << 7;

    // ---- rating counts ----
    const int c0 = (int)__popcll(__ballot(hmv && hr == 0));
    const int c1 = (int)__popcll(__ballot(hmv && hr == 1));
    const int c2 = (int)__popcll(__ballot(hmv && hr == 2));
    const int c3 = (int)__popcll(__ballot(hmv && hr == 3));
    const int c4 = (int)__popcll(__ballot(hmv && hr == 4));

    // ---- read back merged list (ends lcomp lifetime) ----
    int pkA = lc[lane];
    int pkB = lc[64 + (lane & 31)];

    // ---- softmax over 8 group logits from precomputed Q (lanes 0..7) ----
    float sc = (lane < 8) ? Q[nd] : -1e30f;
    float mx = sc;
    mx = fmaxf(mx, __shfl_xor(mx, 1));
    mx = fmaxf(mx, __shfl_xor(mx, 2));
    mx = fmaxf(mx, __shfl_xor(mx, 4));
    float ex = __expf(sc - mx);
    float sm = ex;
    sm += __shfl_xor(sm, 1);
    sm += __shfl_xor(sm, 2);
    sm += __shfl_xor(sm, 4);
    float al = ex / sm;                 // valid on lanes 0..7

    // ---- member-row gathers (8 rows; 2 ushort4 per lane), alpha-weighted ----
    float4 sf4;
    {
        const float a0 = __shfl(al, grp);
        const int   u0 = __shfl(nd, grp);
        const float a1 = __shfl(al, 4 + grp);
        const int   u1 = __shfl(nd, 4 + grp);
        const float4 v0 = bf4_to_f4(*(const ushort4*)(fb + ((unsigned)u0 << 7) + sub * 8));
        const float4 v1 = bf4_to_f4(*(const ushort4*)(fb + ((unsigned)u1 << 7) + sub * 8));
        sf4.x = a0 * v0.x + a1 * v1.x;
        sf4.y = a0 * v0.y + a1 * v1.y;
        sf4.z = a0 * v0.z + a1 * v1.z;
        sf4.w = a0 * v0.w + a1 * v1.w;
    }

    // ---- PASS 1 (real): merged neighbor gathers, 16 rows / iter ----
    float4 nb4 = {0.f, 0.f, 0.f, 0.f};
    for (int base = 0; base < n; base += 16) {
        #pragma unroll
        for (int j = 0; j < 4; ++j) {
            const int cbase = base + j * 4;       // uniform, 4-aligned
            int off;
            if (cbase < 64) off = __shfl(pkA, cbase + grp);
            else            off = __shfl(pkB, cbase - 64 + grp);
            const int idx = cbase + grp;
            const float w = (idx < hc) ? hw : ((idx < n) ? sw : 0.f);
            const float4 v = bf4_to_f4(*(const ushort4*)(fb + (unsigned)off + sub * 8));
            nb4.x += w * v.x; nb4.y += w * v.y;
            nb4.z += w * v.z; nb4.w += w * v.w;
        }
    }

    // ---- PASS 2 (diagnostic): identical loads, dummy accumulator.
    //      memory barrier prevents CSE of the loads; keep-alives prevent DCE.
    asm volatile("" ::: "memory");
    float4 dm4 = {0.f, 0.f, 0.f, 0.f};
    for (int base = 0; base < n; base += 16) {
        #pragma unroll
        for (int j = 0; j < 4; ++j) {
            const int cbase = base + j * 4;
            int off;
            if (cbase < 64) off = __shfl(pkA, cbase + grp);
            else            off = __shfl(pkB, cbase - 64 + grp);
            const int idx = cbase + grp;
            const float w = (idx < hc) ? hw : ((idx < n) ? sw : 0.f);
            const float4 v = bf4_to_f4(*(const ushort4*)(fb + (unsigned)off + sub * 8));
            dm4.x += w * v.x; dm4.y += w * v.y;
            dm4.z += w * v.z; dm4.w += w * v.w;
        }
    }
    asm volatile("" :: "v"(dm4.x), "v"(dm4.y), "v"(dm4.z), "v"(dm4.w));

    // ---- cross-group reduction (sum row-slot partials; all lanes end equal) ----
#define XRED(v4)                                            \
    v4.x += __shfl_xor(v4.x, 16); v4.x += __shfl_xor(v4.x, 32); \
    v4.y += __shfl_xor(v4.y, 16); v4.y += __shfl_xor(v4.y, 32); \
    v4.z += __shfl_xor(v4.z, 16); v4.z += __shfl_xor(v4.z, 32); \
    v4.w += __shfl_xor(v4.w, 16); v4.w += __shfl_xor(v4.w, 32);
    XRED(sf4)
    XRED(nb4)
#undef XRED

    // ---- rating-count correction (scaled by 0.5/hc); re loads late ----
    {
        const float4* re4p = (const float4*)r_embed;
        const float4 re0 = re4p[0 * 16 + sub];
        const float4 re1 = re4p[1 * 16 + sub];
        const float4 re2 = re4p[2 * 16 + sub];
        const float4 re3 = re4p[3 * 16 + sub];
        const float4 re4 = re4p[4 * 16 + sub];
        float f0 = hw * (float)c0, f1 = hw * (float)c1, f2 = hw * (float)c2,
              f3 = hw * (float)c3, f4 = hw * (float)c4;
        nb4.x += f0 * re0.x + f1 * re1.x + f2 * re2.x + f3 * re3.x + f4 * re4.x;
        nb4.y += f0 * re0.y + f1 * re1.y + f2 * re2.y + f3 * re3.y + f4 * re4.y;
        nb4.z += f0 * re0.z + f1 * re1.z + f2 * re2.z + f3 * re3.z + f4 * re4.z;
        nb4.w += f0 * re0.w + f1 * re1.w + f2 * re2.w + f3 * re3.w + f4 * re4.w;
    }

    // ---- park comb row (lcomp dead; wave-local, no barrier) ----
    if (grp == 0) *(float4*)&cb[sub * 4] = sf4;
    if (grp == 1) *(float4*)&cb[64 + sub * 4] = nb4;

    // ---- fused matvec, float4 w1 loads:
    //      lane (grp,sub) accumulates cols 4sub..4sub+3 over k = 4j+grp ----
    float4 p = {0.f, 0.f, 0.f, 0.f};
    #pragma unroll 8
    for (int j = 0; j < 32; ++j) {
        const float  c   = cb[j * 4 + grp];                    // LDS broadcast
        const float4 wv4 = *(const float4*)(w1 + (j * 4 + grp) * 64 + sub * 4);
        p.x += c * wv4.x;
        p.y += c * wv4.y;
        p.z += c * wv4.z;
        p.w += c * wv4.w;
    }
    p.x += __shfl_xor(p.x, 16); p.x += __shfl_xor(p.x, 32);
    p.y += __shfl_xor(p.y, 16); p.y += __shfl_xor(p.y, 32);
    p.z += __shfl_xor(p.z, 16); p.z += __shfl_xor(p.z, 32);
    p.w += __shfl_xor(p.w, 16); p.w += __shfl_xor(p.w, 32);
    if (grp == 0) {
        const float4 bv = *(const float4*)(b1 + sub * 4);
        float4 o;
        o.x = fmaxf(p.x + bv.x, 0.f);
        o.y = fmaxf(p.y + bv.y, 0.f);
        o.z = fmaxf(p.z + bv.z, 0.f);
        o.w = fmaxf(p.w + bv.w, 0.f);
        *(float4*)(out + (size_t)e * 64 + sub * 4) = o;
    }
}

extern "C" void kernel_launch(void* const* d_in, const int* in_sizes, int n_in,
                              void* d_out, int out_size, void* d_ws, size_t ws_size,
                              hipStream_t stream)
{
    const int*   nodes    = (const int*)d_in[0];
    const int*   hu       = (const int*)d_in[1];
    const int*   hr       = (const int*)d_in[2];
    const int*   hm       = (const int*)d_in[3];
    const int*   sa       = (const int*)d_in[4];
    const int*   smk      = (const int*)d_in[5];
    const float* features = (const float*)d_in[6];
    const float* r_embed  = (const float*)d_in[7];
    const float* wg1      = (const float*)d_in[8];
    const float* bg1      = (const float*)d_in[9];
    const float* wg2      = (const float*)d_in[10];
    const float* bg2      = (const float*)d_in[11];
    const float* w1       = (const float*)d_in[12];
    const float* b1       = (const float*)d_in[13];
    float* out = (float*)d_out;

    float*          Q   = (float*)d_ws;                    // 131072 floats (512 KB)
    unsigned short* fbf = (unsigned short*)(Q + 131072);   // 100000*64 bf16 = 12.8 MB

    k0_scores<<<NUSERS / 16, 256, 0, stream>>>(features, wg1, bg1, wg2, bg2, Q, fbf);
    k1_fuse<<<BB / 4, 256, 0, stream>>>(nodes, hu, hr, hm, sa, smk,
                                        fbf, r_embed, Q, w1, b1, out);
}